// Round 9
// baseline (17.332 us; speedup 1.0000x reference)
//
#include <hip/hip_runtime.h>

#pragma float_control(precise, on)
#pragma STDC FP_CONTRACT OFF

#define SIGNAL_LENGTH 2048
#define NUM_ITERATIONS 3
#define STEP_SIZE 0.001f
// 10/4/2048 = 5 * 2^-12, exact in f32
#define DERIV_STEP 0.001220703125f
// Reference (XLA) lowers x / 0.00244140625 to x * RN(409.6) — verified
// bit-exact (round 8 absmax = 0.0). DO NOT change to a true divide.
#define RCP_TWO_DERIV_STEP 409.6f

// Opaque value barrier: pins each f32 intermediate in a VGPR so the compiler
// cannot contract/reassociate/re-lower anything regardless of harness flags.
// Iteration-1 rounding differences amplify ~x1000/iter, so op-for-op f32
// bit-exactness vs the reference is mandatory.
__device__ __forceinline__ float opq(float x) {
    asm volatile("" : "+v"(x));
    return x;
}

// Linear-interp sample, separately-rounded f32, every step pinned.
__device__ __forceinline__ float sample_v9(const float* __restrict__ row, float pos) {
#pragma clang fp contract(off)
    float idx = opq(pos * 2047.0f);
    int il = (int)floorf(idx);
    il = il < 0 ? 0 : (il > SIGNAL_LENGTH - 1 ? SIGNAL_LENGTH - 1 : il);
    int ir = (int)ceilf(idx);
    ir = ir < 0 ? 0 : (ir > SIGNAL_LENGTH - 1 ? SIGNAL_LENGTH - 1 : ir);
    float w_right = opq(idx - (float)il);
    float w_left  = opq(1.0f - w_right);
    float t0 = opq(row[il] * w_left);
    float t1 = opq(row[ir] * w_right);
    return opq(t0 + t1);
}

// Gradient (reciprocal-multiply, matching reference lowering) + curvature
// sign (divisor is a positive constant under any lowering -> numerator sign).
__device__ __forceinline__ void gradcurv_v9(const float* __restrict__ row, float pos,
                                            float& g, bool& curv_neg) {
#pragma clang fp contract(off)
    float pos_l = opq(fminf(fmaxf(opq(pos - DERIV_STEP), 0.0f), 1.0f));
    float pos_r = opq(fminf(fmaxf(opq(pos + DERIV_STEP), 0.0f), 1.0f));
    float v  = sample_v9(row, pos);
    float vl = sample_v9(row, pos_l);
    float vr = sample_v9(row, pos_r);
    float diff = opq(vr - vl);
    g = opq(diff * RCP_TWO_DERIV_STEP);
    float twov = opq(2.0f * v);           // exact (power of 2)
    float num = opq(opq(vr - twov) + vl); // left-to-right
    curv_neg = num < 0.0f;
}

// 2 threads per row: p1 and p2 refinement chains are fully independent until
// the final mid/ordering step. Doubles waves/SIMD (1 -> 2) to hide the
// per-iteration gather round-trip; per-position arithmetic is unchanged, so
// the result stays bit-exact. Pair exchange via __shfl_xor(lane^1).
__global__ void grad_refine_v9_kernel(const float* __restrict__ signal,
                                      const float* __restrict__ peaks,
                                      float* __restrict__ out,
                                      int n_rows) {
#pragma clang fp contract(off)
    int t = blockIdx.x * blockDim.x + threadIdx.x;
    int row_id = t >> 1;
    if (row_id >= n_rows) return;
    int which = t & 1;   // 0 -> p1 (peaks[...,0]), 1 -> p2 (peaks[...,2])

    const float* __restrict__ row = signal + (size_t)row_id * SIGNAL_LENGTH;
    float p = peaks[(size_t)row_id * 3 + (which ? 2 : 0)];

    #pragma unroll
    for (int it = 0; it < NUM_ITERATIONS; ++it) {
        float g;
        bool cneg;
        gradcurv_v9(row, p, g, cneg);
        // a = (-S*g)*mask; mask==1 exact; mask==0 -> +-0 and p+(+-0)==p.
        float a = cneg ? opq(-STEP_SIZE * g) : 0.0f;
        p = opq(fminf(fmaxf(opq(p + a), 0.0f), 1.0f));
    }

    // Exchange within the lane pair (both lanes of a pair are always active:
    // rows are whole pairs).
    float other = __shfl_xor(p, 1, 64);

    if (which == 0) {
        float p1 = p, p2 = other;
        float mid = opq(opq(p1 + p2) * 0.5f);  // /2 == *0.5 exactly
        bool ordered = p1 < p2;
        float o0 = ordered ? p1 : p2;
        float o2 = ordered ? p2 : p1;
        out[(size_t)row_id * 3 + 0] = o0;
        out[(size_t)row_id * 3 + 1] = mid;
        out[(size_t)row_id * 3 + 2] = o2;
    }
}

extern "C" void kernel_launch(void* const* d_in, const int* in_sizes, int n_in,
                              void* d_out, int out_size, void* d_ws, size_t ws_size,
                              hipStream_t stream) {
    // Inputs identified by size: signal = 65536*2048, peaks = 65536*3.
    const float* signal = (const float*)d_in[0];
    const float* peaks  = (const float*)d_in[1];
    if (n_in >= 2 && in_sizes[0] < in_sizes[1]) {
        signal = (const float*)d_in[1];
        peaks  = (const float*)d_in[0];
    }
    float* out = (float*)d_out;

    int n_rows = out_size / 3;
    if (n_rows <= 0) n_rows = 65536;

    int n_threads = 2 * n_rows;
    int block = 256;
    int grid = (n_threads + block - 1) / block;
    grad_refine_v9_kernel<<<grid, block, 0, stream>>>(signal, peaks, out, n_rows);
}

// Round 10
// 11.530 us; speedup vs baseline: 1.5033x; 1.5033x over previous
//
#include <hip/hip_runtime.h>

#pragma float_control(precise, on)
#pragma STDC FP_CONTRACT OFF

#define SIGNAL_LENGTH 2048
#define NUM_ITERATIONS 3
#define STEP_SIZE 0.001f
// 10/4/2048 = 5 * 2^-12, exact in f32
#define DERIV_STEP 0.001220703125f
// Reference (XLA) lowers x / 0.00244140625 to x * RN(409.6) — verified
// bit-exact (round 8 absmax = 0.0). DO NOT change to a true divide.
#define RCP_TWO_DERIV_STEP 409.6f

// Opaque value barrier: pins each f32 intermediate in a VGPR. Iteration-1
// rounding differences amplify ~x1000/iter; op-for-op f32 bit-exactness vs
// the reference is mandatory (verified: round 8 absmax == 0.0).
__device__ __forceinline__ float opq(float x) {
    asm volatile("" : "+v"(x));
    return x;
}

// Select w[o] from a 12-float register window (o in [0,11]).
// All indices compile-time -> pure cndmask tree, no scratch spill.
__device__ __forceinline__ float sel12(const float4& A, const float4& B,
                                       const float4& C, int o) {
    int q = o >> 2;
    int r = o & 3;
    bool q1 = (q == 1), q2 = (q == 2);
    float s0 = q2 ? C.x : (q1 ? B.x : A.x);
    float s1 = q2 ? C.y : (q1 ? B.y : A.y);
    float s2 = q2 ? C.z : (q1 ? B.z : A.z);
    float s3 = q2 ? C.w : (q1 ? B.w : A.w);
    float t0 = (r & 1) ? s1 : s0;
    float t1 = (r & 1) ? s3 : s2;
    return (r & 2) ? t1 : t0;
}

// Linear-interp sample from the register window; arithmetic identical
// (same pinned ops on the same memory values) to the verified v8 path.
__device__ __forceinline__ float sample_win(const float4& A, const float4& B,
                                            const float4& C, int a, float idx) {
#pragma clang fp contract(off)
    int il = (int)floorf(idx);
    il = il < 0 ? 0 : (il > SIGNAL_LENGTH - 1 ? SIGNAL_LENGTH - 1 : il);
    int ir = (int)ceilf(idx);
    ir = ir < 0 ? 0 : (ir > SIGNAL_LENGTH - 1 ? SIGNAL_LENGTH - 1 : ir);
    float w_right = opq(idx - (float)il);
    float w_left  = opq(1.0f - w_right);
    float vl = sel12(A, B, C, il - a);
    float vr = sel12(A, B, C, ir - a);
    float t0 = opq(vl * w_left);
    float t1 = opq(vr * w_right);
    return opq(t0 + t1);
}

// Gradient + curvature sign. The 3 sample points span <= 6 consecutive
// elements; fetch them with 3 aligned float4 loads (12-float window) instead
// of 6 scattered scalar loads -> 3x fewer VMEM requests.
__device__ __forceinline__ void gradcurv_v10(const float* __restrict__ row, float pos,
                                             float& g, bool& curv_neg) {
#pragma clang fp contract(off)
    float pos_l = opq(fminf(fmaxf(opq(pos - DERIV_STEP), 0.0f), 1.0f));
    float pos_r = opq(fminf(fmaxf(opq(pos + DERIV_STEP), 0.0f), 1.0f));
    float idxm = opq(pos   * 2047.0f);
    float idxl = opq(pos_l * 2047.0f);
    float idxr = opq(pos_r * 2047.0f);

    // Leftmost needed index: floor(idxl) (pos_l <= pos <= pos_r, monotone).
    int fl = (int)floorf(idxl);
    fl = fl < 0 ? 0 : (fl > SIGNAL_LENGTH - 1 ? SIGNAL_LENGTH - 1 : fl);
    int a = fl & ~3;                       // 16B-aligned window base
    if (a > SIGNAL_LENGTH - 12) a = SIGNAL_LENGTH - 12;  // cover clipped tail

    // row is 16B-aligned (8KB row stride), a is a multiple of 4.
    const float4* wp = (const float4*)(row + a);
    float4 A = wp[0];
    float4 B = wp[1];
    float4 C = wp[2];

    float v  = sample_win(A, B, C, a, idxm);
    float vl = sample_win(A, B, C, a, idxl);
    float vr = sample_win(A, B, C, a, idxr);

    float diff = opq(vr - vl);
    g = opq(diff * RCP_TWO_DERIV_STEP);
    float twov = opq(2.0f * v);           // exact (power of 2)
    float num = opq(opq(vr - twov) + vl); // left-to-right
    curv_neg = num < 0.0f;
}

__global__ void grad_refine_v10_kernel(const float* __restrict__ signal,
                                       const float* __restrict__ peaks,
                                       float* __restrict__ out,
                                       int n_rows) {
#pragma clang fp contract(off)
    int tid = blockIdx.x * blockDim.x + threadIdx.x;
    if (tid >= n_rows) return;

    const float* __restrict__ row = signal + (size_t)tid * SIGNAL_LENGTH;
    float p1 = peaks[(size_t)tid * 3 + 0];
    float p2 = peaks[(size_t)tid * 3 + 2];

    #pragma unroll
    for (int it = 0; it < NUM_ITERATIONS; ++it) {
        float g1, g2;
        bool n1, n2;
        gradcurv_v10(row, p1, g1, n1);
        gradcurv_v10(row, p2, g2, n2);
        // a = (-S*g)*mask; mask==1 exact; mask==0 -> +-0 and p+(+-0)==p.
        float a1 = n1 ? opq(-STEP_SIZE * g1) : 0.0f;
        float a2 = n2 ? opq(-STEP_SIZE * g2) : 0.0f;
        p1 = opq(fminf(fmaxf(opq(p1 + a1), 0.0f), 1.0f));
        p2 = opq(fminf(fmaxf(opq(p2 + a2), 0.0f), 1.0f));
    }
    float mid = opq(opq(p1 + p2) * 0.5f);  // /2 == *0.5 exactly

    bool ordered = p1 < p2;
    float o0 = ordered ? p1 : p2;
    float o2 = ordered ? p2 : p1;

    out[(size_t)tid * 3 + 0] = o0;
    out[(size_t)tid * 3 + 1] = mid;
    out[(size_t)tid * 3 + 2] = o2;
}

extern "C" void kernel_launch(void* const* d_in, const int* in_sizes, int n_in,
                              void* d_out, int out_size, void* d_ws, size_t ws_size,
                              hipStream_t stream) {
    // Inputs identified by size: signal = 65536*2048, peaks = 65536*3.
    const float* signal = (const float*)d_in[0];
    const float* peaks  = (const float*)d_in[1];
    if (n_in >= 2 && in_sizes[0] < in_sizes[1]) {
        signal = (const float*)d_in[1];
        peaks  = (const float*)d_in[0];
    }
    float* out = (float*)d_out;

    int n_rows = out_size / 3;
    if (n_rows <= 0) n_rows = 65536;

    int block = 256;
    int grid = (n_rows + block - 1) / block;
    grad_refine_v10_kernel<<<grid, block, 0, stream>>>(signal, peaks, out, n_rows);
}